// Round 4
// baseline (300.476 us; speedup 1.0000x reference)
//
#include <hip/hip_runtime.h>

// Problem constants: B=2, L=2048, E=1024, H=16, D=64
// softmax over QUERY axis (columns of the [L,M] score matrix per head).
//
// Pipeline: x->f16; W->W^T f16; fused QKV GEMM (Q pre-scaled by log2e);
// column stats (base-2 max + 1/Z, per-lane online, deferred reduce);
// V' = V * rz (fold normalizer into V); attn: P=exp2(S'-c'), O = P V'.

typedef _Float16 f16x8 __attribute__((ext_vector_type(8)));
typedef _Float16 f16x4 __attribute__((ext_vector_type(4)));
typedef float f32x4 __attribute__((ext_vector_type(4)));

#define MFMA(a, b, c) __builtin_amdgcn_mfma_f32_16x16x32_f16((a), (b), (c), 0, 0, 0)
#define LOG2E 1.4426950408889634f

// ---------------------------------------------------------------------------
// Kernel 1: fp32 -> f16 convert of x  (4096x1024)
// ---------------------------------------------------------------------------
__global__ __launch_bounds__(256) void k_convert_x(const float* __restrict__ x,
                                                   _Float16* __restrict__ xb) {
    int i = (blockIdx.x * 256 + threadIdx.x) * 4;
    float4 f = *(const float4*)(x + i);
    f16x4 o = {(_Float16)f.x, (_Float16)f.y, (_Float16)f.z, (_Float16)f.w};
    *(f16x4*)(xb + i) = o;
}

// ---------------------------------------------------------------------------
// Kernel 2: W (k-major [E][E]) -> W^T f16 ([3*E rows = n][E cols = k])
// ---------------------------------------------------------------------------
__global__ __launch_bounds__(256) void k_convert_wt(const float* __restrict__ Wq,
                                                    const float* __restrict__ Wk,
                                                    const float* __restrict__ Wv,
                                                    _Float16* __restrict__ wbt) {
    const int jz = blockIdx.z;
    const float* W = (jz == 0) ? Wq : (jz == 1) ? Wk : Wv;
    __shared__ float tile[64][65];
    const int k0 = blockIdx.y * 64, n0 = blockIdx.x * 64;
    for (int e = threadIdx.x; e < 4096; e += 256) {
        int r = e >> 6, c = e & 63;
        tile[r][c] = W[(k0 + r) * 1024 + n0 + c];
    }
    __syncthreads();
    for (int e = threadIdx.x; e < 4096; e += 256) {
        int r = e >> 6, c = e & 63;  // r: n-offset, c: k-offset
        wbt[((size_t)jz * 1024 + n0 + r) * 1024 + k0 + c] = (_Float16)tile[c][r];
    }
}

// ---------------------------------------------------------------------------
// Kernel 3: fused QKV projection GEMM. Q gets *LOG2E (exp2-domain softmax).
// ---------------------------------------------------------------------------
__global__ __launch_bounds__(256) void k_proj_gemm(const _Float16* __restrict__ xb,
                                                   const _Float16* __restrict__ wbt,
                                                   const float* __restrict__ bq,
                                                   const float* __restrict__ bk,
                                                   const float* __restrict__ bv,
                                                   _Float16* __restrict__ Qb,
                                                   _Float16* __restrict__ Kb,
                                                   _Float16* __restrict__ Vt) {
    const int n0 = blockIdx.x * 128;  // 24 blocks -> N=3072
    const int m0 = blockIdx.y * 128;  // 32 blocks -> M=4096
    __shared__ _Float16 As[128][40];
    __shared__ _Float16 Bs[128][40];
    const int tid = threadIdx.x;
    const int lane = tid & 63, wv = tid >> 6;
    const int l15 = lane & 15, quad = lane >> 4;
    const int wr = wv >> 1, wc = wv & 1;

    f32x4 acc[4][4] = {};
    for (int k0 = 0; k0 < 1024; k0 += 32) {
        __syncthreads();
        for (int j = 0; j < 2; ++j) {
            int chunk = tid + 256 * j;  // 0..511
            int row = chunk >> 2, c = chunk & 3;
            *(uint4*)&As[row][c * 8] = *(const uint4*)&xb[(size_t)(m0 + row) * 1024 + k0 + c * 8];
            *(uint4*)&Bs[row][c * 8] = *(const uint4*)&wbt[(size_t)(n0 + row) * 1024 + k0 + c * 8];
        }
        __syncthreads();
        f16x8 af[4], bf[4];
        for (int i = 0; i < 4; ++i) {
            af[i] = *(const f16x8*)&As[wr * 64 + i * 16 + l15][quad * 8];
            bf[i] = *(const f16x8*)&Bs[wc * 64 + i * 16 + l15][quad * 8];
        }
        for (int i = 0; i < 4; ++i)
            for (int j = 0; j < 4; ++j)
                acc[i][j] = MFMA(af[i], bf[j], acc[i][j]);
    }

    const int proj = n0 >> 10;
    const float* bias = (proj == 0) ? bq : (proj == 1) ? bk : bv;
    const float scale = (proj == 0) ? LOG2E : 1.0f;
    for (int j = 0; j < 4; ++j) {
        int n = n0 + wc * 64 + j * 16 + l15;
        int nn = n & 1023;
        float bsv = bias[nn];
        int h = nn >> 6, d = nn & 63;
        for (int i = 0; i < 4; ++i) {
            for (int r = 0; r < 4; ++r) {
                int t = m0 + wr * 64 + i * 16 + quad * 4 + r;
                int b = t >> 11, l = t & 2047;
                _Float16 val = (_Float16)((acc[i][j][r] + bsv) * scale);
                int bh = b * 16 + h;
                if (proj == 0)
                    Qb[((size_t)bh * 2048 + l) * 64 + d] = val;
                else if (proj == 1)
                    Kb[((size_t)bh * 2048 + l) * 64 + d] = val;
                else
                    Vt[((size_t)bh * 64 + d) * 2048 + l] = val;
            }
        }
    }
}

// ---------------------------------------------------------------------------
// Kernel 4: column stats (base-2). Per column m: c'_m = max_l S', and
// rz = 1 / sum_l exp2(S'-c'). Per-lane online (the 4 acc regs of a lane are
// the SAME column) — cross (wave,quad) reduction deferred to the end.
// ---------------------------------------------------------------------------
__global__ __launch_bounds__(256) void k_stats(const _Float16* __restrict__ Qb,
                                               const _Float16* __restrict__ Kb,
                                               float* __restrict__ colmax,
                                               float* __restrict__ colrz) {
    const int m0 = blockIdx.x * 64;  // 32 m-tiles
    const int bh = blockIdx.y;       // 32 heads
    __shared__ _Float16 Ks[64][72];
    __shared__ _Float16 Qs[64][72];
    __shared__ float red[16][64][2];  // [wv*4+quad][col][max,sum]
    const int tid = threadIdx.x;
    const int lane = tid & 63, wv = tid >> 6, l15 = lane & 15, quad = lane >> 4;

    for (int it = 0; it < 2; ++it) {
        int chunk = tid + 256 * it;
        int row = chunk >> 3, c = chunk & 7;
        *(uint4*)&Ks[row][c * 8] = *(const uint4*)&Kb[((size_t)bh * 2048 + m0 + row) * 64 + c * 8];
    }
    float runmax[4], runsum[4];
    for (int s = 0; s < 4; ++s) { runmax[s] = -__builtin_inff(); runsum[s] = 0.f; }
    __syncthreads();
    f16x8 bf[4][2];
    for (int s = 0; s < 4; ++s)
        for (int kc = 0; kc < 2; ++kc)
            bf[s][kc] = *(const f16x8*)&Ks[s * 16 + l15][kc * 32 + quad * 8];

    for (int l0 = 0; l0 < 2048; l0 += 64) {
        __syncthreads();
        for (int it = 0; it < 2; ++it) {
            int chunk = tid + 256 * it;
            int row = chunk >> 3, c = chunk & 7;
            *(uint4*)&Qs[row][c * 8] = *(const uint4*)&Qb[((size_t)bh * 2048 + l0 + row) * 64 + c * 8];
        }
        __syncthreads();
        f16x8 af0 = *(const f16x8*)&Qs[wv * 16 + l15][quad * 8];
        f16x8 af1 = *(const f16x8*)&Qs[wv * 16 + l15][32 + quad * 8];
        for (int s = 0; s < 4; ++s) {
            f32x4 a = {};
            a = MFMA(af0, bf[s][0], a);
            a = MFMA(af1, bf[s][1], a);
            float tmax = fmaxf(fmaxf(a[0], a[1]), fmaxf(a[2], a[3]));
            float nm = fmaxf(runmax[s], tmax);
            float ssum = exp2f(a[0] - nm) + exp2f(a[1] - nm) +
                         exp2f(a[2] - nm) + exp2f(a[3] - nm);
            runsum[s] = runsum[s] * exp2f(runmax[s] - nm) + ssum;
            runmax[s] = nm;
        }
    }
    __syncthreads();
    for (int s = 0; s < 4; ++s) {
        red[wv * 4 + quad][s * 16 + l15][0] = runmax[s];
        red[wv * 4 + quad][s * 16 + l15][1] = runsum[s];
    }
    __syncthreads();
    if (tid < 64) {
        float m = red[0][tid][0];
        for (int i = 1; i < 16; ++i) m = fmaxf(m, red[i][tid][0]);
        float z = 0.f;
        for (int i = 0; i < 16; ++i) z += red[i][tid][1] * exp2f(red[i][tid][0] - m);
        colmax[bh * 2048 + m0 + tid] = m;
        colrz[bh * 2048 + m0 + tid] = 1.0f / z;
    }
}

// ---------------------------------------------------------------------------
// Kernel 4b: fold the normalizer into V:  Vt[bh][d][m] *= rz[bh][m].
// ---------------------------------------------------------------------------
__global__ __launch_bounds__(256) void k_scale_v(_Float16* __restrict__ Vt,
                                                 const float* __restrict__ colrz) {
    int idx = (blockIdx.x * 256 + threadIdx.x) * 8;  // 4194304 f16 elems total
    int m = idx & 2047;
    int bh = idx >> 17;  // 2048*64 per head
    const float* rz = colrz + bh * 2048 + m;
    f16x8 v = *(f16x8*)&Vt[idx];
    float4 r0 = *(const float4*)(rz);
    float4 r1 = *(const float4*)(rz + 4);
    f16x8 o;
    o[0] = (_Float16)((float)v[0] * r0.x);
    o[1] = (_Float16)((float)v[1] * r0.y);
    o[2] = (_Float16)((float)v[2] * r0.z);
    o[3] = (_Float16)((float)v[3] * r0.w);
    o[4] = (_Float16)((float)v[4] * r1.x);
    o[5] = (_Float16)((float)v[5] * r1.y);
    o[6] = (_Float16)((float)v[6] * r1.z);
    o[7] = (_Float16)((float)v[7] * r1.w);
    *(f16x8*)&Vt[idx] = o;
}

// ---------------------------------------------------------------------------
// Kernel 5: output. 64 q-rows/block; m-chunk 64; 2 barriers per chunk.
// P = exp2(S'-c') (unnormalized, <=1), O = P V' accumulated fp32.
// ---------------------------------------------------------------------------
__global__ __launch_bounds__(256) void k_attn(const _Float16* __restrict__ Qb,
                                              const _Float16* __restrict__ Kb,
                                              const _Float16* __restrict__ Vt,
                                              const float* __restrict__ colmax,
                                              float* __restrict__ out) {
    const int l0 = blockIdx.x * 64;  // 32 l-tiles
    const int bh = blockIdx.y;       // 32 heads
    const int b = bh >> 4, h = bh & 15;
    __shared__ _Float16 Qs[64][72];     // [l][d]
    __shared__ _Float16 Ks[64][72];     // [m][d]
    __shared__ _Float16 Vs[64][72];     // [d][m]
    __shared__ _Float16 Ps[4][16][72];  // per-wave P scratch [l][m] (private!)
    const int tid = threadIdx.x, lane = tid & 63, wv = tid >> 6;
    const int l15 = lane & 15, quad = lane >> 4;
    const float* cmax = colmax + bh * 2048;

    for (int it = 0; it < 2; ++it) {
        int chunk = tid + 256 * it;
        int row = chunk >> 3, c = chunk & 7;
        *(uint4*)&Qs[row][c * 8] = *(const uint4*)&Qb[((size_t)bh * 2048 + l0 + row) * 64 + c * 8];
    }
    __syncthreads();
    f16x8 qf0 = *(const f16x8*)&Qs[wv * 16 + l15][quad * 8];
    f16x8 qf1 = *(const f16x8*)&Qs[wv * 16 + l15][32 + quad * 8];

    f32x4 oacc[4] = {};
    for (int m0 = 0; m0 < 2048; m0 += 64) {
        __syncthreads();  // prior-iter reads of Ks/Vs complete
        for (int it = 0; it < 2; ++it) {
            int chunk = tid + 256 * it;
            int row = chunk >> 3, c = chunk & 7;
            *(uint4*)&Ks[row][c * 8] = *(const uint4*)&Kb[((size_t)bh * 2048 + m0 + row) * 64 + c * 8];
            *(uint4*)&Vs[row][c * 8] = *(const uint4*)&Vt[((size_t)bh * 64 + row) * 2048 + m0 + c * 8];
        }
        __syncthreads();
        // S' = Q' K^T : per wave [16 l][64 m]; P = exp2(S'-c') -> LDS [l][m]
        for (int s = 0; s < 4; ++s) {
            f32x4 a = {};
            f16x8 kf0 = *(const f16x8*)&Ks[s * 16 + l15][quad * 8];
            f16x8 kf1 = *(const f16x8*)&Ks[s * 16 + l15][32 + quad * 8];
            a = MFMA(qf0, kf0, a);
            a = MFMA(qf1, kf1, a);
            float c = cmax[m0 + s * 16 + l15];
            Ps[wv][quad * 4 + 0][s * 16 + l15] = (_Float16)exp2f(a[0] - c);
            Ps[wv][quad * 4 + 1][s * 16 + l15] = (_Float16)exp2f(a[1] - c);
            Ps[wv][quad * 4 + 2][s * 16 + l15] = (_Float16)exp2f(a[2] - c);
            Ps[wv][quad * 4 + 3][s * 16 + l15] = (_Float16)exp2f(a[3] - c);
        }
        // PV: Ps is per-wave private -> no barrier; same-array dep orders DS ops.
        f16x8 pf0 = *(const f16x8*)&Ps[wv][l15][quad * 8];
        f16x8 pf1 = *(const f16x8*)&Ps[wv][l15][32 + quad * 8];
        for (int dt = 0; dt < 4; ++dt) {
            f16x8 vf0 = *(const f16x8*)&Vs[dt * 16 + l15][quad * 8];
            f16x8 vf1 = *(const f16x8*)&Vs[dt * 16 + l15][32 + quad * 8];
            oacc[dt] = MFMA(pf0, vf0, oacc[dt]);
            oacc[dt] = MFMA(pf1, vf1, oacc[dt]);
        }
    }
    for (int dt = 0; dt < 4; ++dt)
        for (int r = 0; r < 4; ++r) {
            int l = l0 + wv * 16 + quad * 4 + r;
            out[((size_t)(b * 2048 + l)) * 1024 + h * 64 + dt * 16 + l15] = oacc[dt][r];
        }
}

// ---------------------------------------------------------------------------
// Workspace: xb 8MB | wbt 6MB | Qb 8MB | Kb 8MB | Vt 8MB | colmax 256K | colrz 256K
// ---------------------------------------------------------------------------
extern "C" void kernel_launch(void* const* d_in, const int* in_sizes, int n_in,
                              void* d_out, int out_size, void* d_ws, size_t ws_size,
                              hipStream_t stream) {
    const float* x  = (const float*)d_in[0];
    const float* Wq = (const float*)d_in[1];
    const float* bq = (const float*)d_in[2];
    const float* Wk = (const float*)d_in[3];
    const float* bk = (const float*)d_in[4];
    const float* Wv = (const float*)d_in[5];
    const float* bv = (const float*)d_in[6];
    float* out = (float*)d_out;

    char* w = (char*)d_ws;
    _Float16* xb  = (_Float16*)(w);
    _Float16* wbt = (_Float16*)(w + (size_t)(8 << 20));
    _Float16* Qb  = (_Float16*)(w + (size_t)(14 << 20));
    _Float16* Kb  = (_Float16*)(w + (size_t)(22 << 20));
    _Float16* Vt  = (_Float16*)(w + (size_t)(30 << 20));
    float* colmax = (float*)(w + (size_t)(38 << 20));
    float* colrz  = (float*)(w + (size_t)(38 << 20) + (256 << 10));

    k_convert_x<<<4096, 256, 0, stream>>>(x, xb);
    k_convert_wt<<<dim3(16, 16, 3), 256, 0, stream>>>(Wq, Wk, Wv, wbt);
    k_proj_gemm<<<dim3(24, 32), 256, 0, stream>>>(xb, wbt, bq, bk, bv, Qb, Kb, Vt);
    k_stats<<<dim3(32, 32), 256, 0, stream>>>(Qb, Kb, colmax, colrz);
    k_scale_v<<<2048, 256, 0, stream>>>(Vt, colrz);
    k_attn<<<dim3(32, 32), 256, 0, stream>>>(Qb, Kb, Vt, colmax, out);
}

// Round 5
// 289.306 us; speedup vs baseline: 1.0386x; 1.0386x over previous
//
#include <hip/hip_runtime.h>

// Problem constants: B=2, L=2048, E=1024, H=16, D=64
// softmax over QUERY axis (columns of the [L,M] score matrix per head).
//
// Pipeline: x->f16; W->W^T f16; fused QKV GEMM (Q pre-scaled by log2e, all
// outputs row-major); V transpose; column stats Z_m = sum_l exp2(S') with
// NO max (fp32 range suffices), c_m = log2(Z_m); attn: P = exp2(S'-c) is
// already normalized, O = P V.

typedef _Float16 f16x8 __attribute__((ext_vector_type(8)));
typedef _Float16 f16x4 __attribute__((ext_vector_type(4)));
typedef float f32x4 __attribute__((ext_vector_type(4)));

#define MFMA(a, b, c) __builtin_amdgcn_mfma_f32_16x16x32_f16((a), (b), (c), 0, 0, 0)
#define LOG2E 1.4426950408889634f

// ---------------------------------------------------------------------------
// Kernel 1: fp32 -> f16 convert of x  (4096x1024)
// ---------------------------------------------------------------------------
__global__ __launch_bounds__(256) void k_convert_x(const float* __restrict__ x,
                                                   _Float16* __restrict__ xb) {
    int i = (blockIdx.x * 256 + threadIdx.x) * 4;
    float4 f = *(const float4*)(x + i);
    f16x4 o = {(_Float16)f.x, (_Float16)f.y, (_Float16)f.z, (_Float16)f.w};
    *(f16x4*)(xb + i) = o;
}

// ---------------------------------------------------------------------------
// Kernel 2: W (k-major [E][E]) -> W^T f16 ([3*E rows = n][E cols = k])
// ---------------------------------------------------------------------------
__global__ __launch_bounds__(256) void k_convert_wt(const float* __restrict__ Wq,
                                                    const float* __restrict__ Wk,
                                                    const float* __restrict__ Wv,
                                                    _Float16* __restrict__ wbt) {
    const int jz = blockIdx.z;
    const float* W = (jz == 0) ? Wq : (jz == 1) ? Wk : Wv;
    __shared__ float tile[64][65];
    const int k0 = blockIdx.y * 64, n0 = blockIdx.x * 64;
    for (int e = threadIdx.x; e < 4096; e += 256) {
        int r = e >> 6, c = e & 63;
        tile[r][c] = W[(k0 + r) * 1024 + n0 + c];
    }
    __syncthreads();
    for (int e = threadIdx.x; e < 4096; e += 256) {
        int r = e >> 6, c = e & 63;  // r: n-offset, c: k-offset
        wbt[((size_t)jz * 1024 + n0 + r) * 1024 + k0 + c] = (_Float16)tile[c][r];
    }
}

// ---------------------------------------------------------------------------
// Kernel 3: fused QKV projection GEMM. Q gets *LOG2E. All outputs row-major
// [BH][L][64] (fully coalesced stores).
// ---------------------------------------------------------------------------
__global__ __launch_bounds__(256) void k_proj_gemm(const _Float16* __restrict__ xb,
                                                   const _Float16* __restrict__ wbt,
                                                   const float* __restrict__ bq,
                                                   const float* __restrict__ bk,
                                                   const float* __restrict__ bv,
                                                   _Float16* __restrict__ Qb,
                                                   _Float16* __restrict__ Kb,
                                                   _Float16* __restrict__ Vr) {
    const int n0 = blockIdx.x * 128;  // 24 blocks -> N=3072
    const int m0 = blockIdx.y * 128;  // 32 blocks -> M=4096
    __shared__ _Float16 As[128][40];
    __shared__ _Float16 Bs[128][40];
    const int tid = threadIdx.x;
    const int lane = tid & 63, wv = tid >> 6;
    const int l15 = lane & 15, quad = lane >> 4;
    const int wr = wv >> 1, wc = wv & 1;

    f32x4 acc[4][4] = {};
    for (int k0 = 0; k0 < 1024; k0 += 32) {
        __syncthreads();
        for (int j = 0; j < 2; ++j) {
            int chunk = tid + 256 * j;  // 0..511
            int row = chunk >> 2, c = chunk & 3;
            *(uint4*)&As[row][c * 8] = *(const uint4*)&xb[(size_t)(m0 + row) * 1024 + k0 + c * 8];
            *(uint4*)&Bs[row][c * 8] = *(const uint4*)&wbt[(size_t)(n0 + row) * 1024 + k0 + c * 8];
        }
        __syncthreads();
        f16x8 af[4], bf[4];
        for (int i = 0; i < 4; ++i) {
            af[i] = *(const f16x8*)&As[wr * 64 + i * 16 + l15][quad * 8];
            bf[i] = *(const f16x8*)&Bs[wc * 64 + i * 16 + l15][quad * 8];
        }
        for (int i = 0; i < 4; ++i)
            for (int j = 0; j < 4; ++j)
                acc[i][j] = MFMA(af[i], bf[j], acc[i][j]);
    }

    const int proj = n0 >> 10;
    const float* bias = (proj == 0) ? bq : (proj == 1) ? bk : bv;
    const float scale = (proj == 0) ? LOG2E : 1.0f;
    _Float16* dst = (proj == 0) ? Qb : (proj == 1) ? Kb : Vr;
    for (int j = 0; j < 4; ++j) {
        int n = n0 + wc * 64 + j * 16 + l15;
        int nn = n & 1023;
        float bsv = bias[nn];
        int h = nn >> 6, d = nn & 63;
        for (int i = 0; i < 4; ++i) {
            for (int r = 0; r < 4; ++r) {
                int t = m0 + wr * 64 + i * 16 + quad * 4 + r;
                int b = t >> 11, l = t & 2047;
                int bh = b * 16 + h;
                dst[((size_t)bh * 2048 + l) * 64 + d] = (_Float16)((acc[i][j][r] + bsv) * scale);
            }
        }
    }
}

// ---------------------------------------------------------------------------
// Kernel 3b: V [bh][l][d] -> Vt [bh][d][l], tiled transpose via LDS.
// ---------------------------------------------------------------------------
__global__ __launch_bounds__(256) void k_transpose_v(const _Float16* __restrict__ V,
                                                     _Float16* __restrict__ Vt) {
    __shared__ _Float16 t[64][68];  // [d][l] after scatter
    const int l0 = blockIdx.x * 64, bh = blockIdx.y, tid = threadIdx.x;
    for (int it = 0; it < 2; ++it) {
        int chunk = tid + 256 * it;
        int row = chunk >> 3, c = chunk & 7;  // row: l-offset, c*8: d
        f16x8 v = *(const f16x8*)&V[((size_t)bh * 2048 + l0 + row) * 64 + c * 8];
        for (int j = 0; j < 8; ++j) t[c * 8 + j][row] = v[j];
    }
    __syncthreads();
    for (int it = 0; it < 2; ++it) {
        int chunk = tid + 256 * it;
        int d = chunk >> 3, c = chunk & 7;  // c*8: l-offset
        f16x8 o = *(const f16x8*)&t[d][c * 8];
        *(f16x8*)&Vt[((size_t)bh * 64 + d) * 2048 + l0 + c * 8] = o;
    }
}

// ---------------------------------------------------------------------------
// Kernel 4: column stats. Z_m = sum_l exp2(S') in fp32 (no max needed);
// colc = log2(Z). Barrier-free main loop: K fragments resident in regs
// (direct global load), Q fragments loaded directly from global.
// ---------------------------------------------------------------------------
__global__ __launch_bounds__(256) void k_stats(const _Float16* __restrict__ Qb,
                                               const _Float16* __restrict__ Kb,
                                               float* __restrict__ colc) {
    const int m0 = blockIdx.x * 64;  // 32 m-tiles
    const int bh = blockIdx.y;       // 32 heads
    const int tid = threadIdx.x;
    const int lane = tid & 63, wv = tid >> 6, l15 = lane & 15, quad = lane >> 4;
    __shared__ float red[16][64];

    // K^T B-fragments, loop-invariant: B[k=d][n=m] = K[m][d]
    f16x8 bf[4][2];
    for (int s = 0; s < 4; ++s)
        for (int kc = 0; kc < 2; ++kc)
            bf[s][kc] = *(const f16x8*)&Kb[((size_t)bh * 2048 + m0 + s * 16 + l15) * 64 + kc * 32 + quad * 8];

    float runsum[4] = {0.f, 0.f, 0.f, 0.f};
    const _Float16* qp = Qb + ((size_t)bh * 2048 + wv * 16 + l15) * 64 + quad * 8;
    for (int l0 = 0; l0 < 2048; l0 += 64) {
        f16x8 af0 = *(const f16x8*)(qp);
        f16x8 af1 = *(const f16x8*)(qp + 32);
        qp += 64 * 64;
        for (int s = 0; s < 4; ++s) {
            f32x4 a = {};
            a = MFMA(af0, bf[s][0], a);
            a = MFMA(af1, bf[s][1], a);
            runsum[s] += exp2f(a[0]) + exp2f(a[1]) + exp2f(a[2]) + exp2f(a[3]);
        }
    }
    for (int s = 0; s < 4; ++s)
        red[wv * 4 + quad][s * 16 + l15] = runsum[s];
    __syncthreads();
    if (tid < 64) {
        float z = 0.f;
        for (int i = 0; i < 16; ++i) z += red[i][tid];
        colc[bh * 2048 + m0 + tid] = log2f(z);
    }
}

// ---------------------------------------------------------------------------
// Kernel 5: output. 64 q-rows/block; m-chunk 64; 2 barriers per chunk.
// P = exp2(S'-c) is already normalized (sum over l = 1); O = P V in fp32.
// ---------------------------------------------------------------------------
__global__ __launch_bounds__(256) void k_attn(const _Float16* __restrict__ Qb,
                                              const _Float16* __restrict__ Kb,
                                              const _Float16* __restrict__ Vt,
                                              const float* __restrict__ colc,
                                              float* __restrict__ out) {
    const int l0 = blockIdx.x * 64;  // 32 l-tiles
    const int bh = blockIdx.y;       // 32 heads
    const int b = bh >> 4, h = bh & 15;
    __shared__ _Float16 Ks[64][72];     // [m][d]
    __shared__ _Float16 Vs[64][72];     // [d][m]
    __shared__ _Float16 Ps[4][16][72];  // per-wave P scratch [l][m] (private)
    const int tid = threadIdx.x, lane = tid & 63, wv = tid >> 6;
    const int l15 = lane & 15, quad = lane >> 4;
    const float* cc = colc + bh * 2048;

    // Q fragments: direct global load (wave's rows are l0+wv*16+l15)
    f16x8 qf0 = *(const f16x8*)&Qb[((size_t)bh * 2048 + l0 + wv * 16 + l15) * 64 + quad * 8];
    f16x8 qf1 = *(const f16x8*)&Qb[((size_t)bh * 2048 + l0 + wv * 16 + l15) * 64 + 32 + quad * 8];

    f32x4 oacc[4] = {};
    for (int m0 = 0; m0 < 2048; m0 += 64) {
        __syncthreads();  // prior-iter reads of Ks/Vs complete
        for (int it = 0; it < 2; ++it) {
            int chunk = tid + 256 * it;
            int row = chunk >> 3, c = chunk & 7;
            *(uint4*)&Ks[row][c * 8] = *(const uint4*)&Kb[((size_t)bh * 2048 + m0 + row) * 64 + c * 8];
            *(uint4*)&Vs[row][c * 8] = *(const uint4*)&Vt[((size_t)bh * 64 + row) * 2048 + m0 + c * 8];
        }
        __syncthreads();
        // S' = Q' K^T : per wave [16 l][64 m]; P = exp2(S'-c) -> LDS [l][m]
        for (int s = 0; s < 4; ++s) {
            f32x4 a = {};
            f16x8 kf0 = *(const f16x8*)&Ks[s * 16 + l15][quad * 8];
            f16x8 kf1 = *(const f16x8*)&Ks[s * 16 + l15][32 + quad * 8];
            a = MFMA(qf0, kf0, a);
            a = MFMA(qf1, kf1, a);
            float c = cc[m0 + s * 16 + l15];
            Ps[wv][quad * 4 + 0][s * 16 + l15] = (_Float16)exp2f(a[0] - c);
            Ps[wv][quad * 4 + 1][s * 16 + l15] = (_Float16)exp2f(a[1] - c);
            Ps[wv][quad * 4 + 2][s * 16 + l15] = (_Float16)exp2f(a[2] - c);
            Ps[wv][quad * 4 + 3][s * 16 + l15] = (_Float16)exp2f(a[3] - c);
        }
        // PV: Ps is per-wave private -> no barrier; same-array dep orders DS ops.
        f16x8 pf0 = *(const f16x8*)&Ps[wv][l15][quad * 8];
        f16x8 pf1 = *(const f16x8*)&Ps[wv][l15][32 + quad * 8];
        for (int dt = 0; dt < 4; ++dt) {
            f16x8 vf0 = *(const f16x8*)&Vs[dt * 16 + l15][quad * 8];
            f16x8 vf1 = *(const f16x8*)&Vs[dt * 16 + l15][32 + quad * 8];
            oacc[dt] = MFMA(pf0, vf0, oacc[dt]);
            oacc[dt] = MFMA(pf1, vf1, oacc[dt]);
        }
    }
    for (int dt = 0; dt < 4; ++dt)
        for (int r = 0; r < 4; ++r) {
            int l = l0 + wv * 16 + quad * 4 + r;
            out[((size_t)(b * 2048 + l)) * 1024 + h * 64 + dt * 16 + l15] = oacc[dt][r];
        }
}

// ---------------------------------------------------------------------------
// Workspace layout (reuses xb region for Vt; xb dead after proj):
//  0    xb (8MB) -> later Vt (8MB)
//  8MB  wbt (6MB)
// 14MB  Qb (8MB)
// 22MB  Kb (8MB)
// 30MB  Vr (8MB, row-major V)
// 38MB  colc (256KB)
// ---------------------------------------------------------------------------
extern "C" void kernel_launch(void* const* d_in, const int* in_sizes, int n_in,
                              void* d_out, int out_size, void* d_ws, size_t ws_size,
                              hipStream_t stream) {
    const float* x  = (const float*)d_in[0];
    const float* Wq = (const float*)d_in[1];
    const float* bq = (const float*)d_in[2];
    const float* Wk = (const float*)d_in[3];
    const float* bk = (const float*)d_in[4];
    const float* Wv = (const float*)d_in[5];
    const float* bv = (const float*)d_in[6];
    float* out = (float*)d_out;

    char* w = (char*)d_ws;
    _Float16* xb  = (_Float16*)(w);
    _Float16* Vt  = (_Float16*)(w);  // reuse: xb dead after proj
    _Float16* wbt = (_Float16*)(w + (size_t)(8 << 20));
    _Float16* Qb  = (_Float16*)(w + (size_t)(14 << 20));
    _Float16* Kb  = (_Float16*)(w + (size_t)(22 << 20));
    _Float16* Vr  = (_Float16*)(w + (size_t)(30 << 20));
    float* colc   = (float*)(w + (size_t)(38 << 20));

    k_convert_x<<<4096, 256, 0, stream>>>(x, xb);
    k_convert_wt<<<dim3(16, 16, 3), 256, 0, stream>>>(Wq, Wk, Wv, wbt);
    k_proj_gemm<<<dim3(24, 32), 256, 0, stream>>>(xb, wbt, bq, bk, bv, Qb, Kb, Vr);
    k_transpose_v<<<dim3(32, 32), 256, 0, stream>>>(Vr, Vt);
    k_stats<<<dim3(32, 32), 256, 0, stream>>>(Qb, Kb, colc);
    k_attn<<<dim3(32, 32), 256, 0, stream>>>(Qb, Kb, Vt, colc, out);
}